// Round 4
// baseline (358.858 us; speedup 1.0000x reference)
//
#include <hip/hip_runtime.h>

// ============================================================================
// INSTRUMENTATION ROUND: Round-3 kernel + ~35us dependent-FMA tail delay.
// Purpose: push kernel dur above the ~75us poison fills so it lands in the
// rocprof top-5 table and we get its FETCH/WRITE/VALUBusy/Occupancy counters
// (traffic counters are slowdown-invariant). Revert the delay next round.
// ============================================================================

// Problem constants
#define R_PIX 123904            // 352*352
#define NVIEW 8                 // B*V
#define NPIX  (R_PIX * (size_t)NVIEW)   // 991232

// Output element offsets (flat, fp32 elements)
#define OFF_MEANS  ((size_t)0)
#define OFF_COV    ((size_t)(3  * NPIX))
#define OFF_SCALES ((size_t)(12 * NPIX))
#define OFF_ROT    ((size_t)(15 * NPIX))
#define OFF_HARM   ((size_t)(19 * NPIX))
#define OFF_OPAC   ((size_t)(31 * NPIX))

#define SLICE_DW 1216
#define LDS_DW   (SLICE_DW * 4)   // 19 KiB

typedef float f4v __attribute__((ext_vector_type(4)));

__device__ __forceinline__ void nt_store4(float* p, float x, float y, float z, float w) {
    f4v v = { x, y, z, w };
    __builtin_nontemporal_store(v, (f4v*)p);
}

__device__ __forceinline__ void g2lds16(const void* g, void* l) {
    __builtin_amdgcn_global_load_lds(
        (__attribute__((address_space(1))) void*)g,
        (__attribute__((address_space(3))) void*)l,
        16, 0, 0);
}

__device__ __forceinline__ void lds_fence() {
    asm volatile("s_waitcnt lgkmcnt(0)" ::: "memory");
}

__global__ __launch_bounds__(256) void gaussian_adapter_kernel(
    const float* __restrict__ extr,
    const float* __restrict__ intr,
    const float* __restrict__ coords,
    const float* __restrict__ depths,
    const float* __restrict__ opac,
    const float* __restrict__ raw,
    const float* __restrict__ imgs,
    const float* __restrict__ shmask,
    float* __restrict__ out)
{
    const int t    = threadIdx.x;
    const int lane = t & 63;
    const int w    = t >> 6;
    const int bv   = blockIdx.y;
    const int bp0  = blockIdx.x * 256;
    const size_t base_pix = (size_t)bv * R_PIX + bp0;
    const int p   = bp0 + t;
    const size_t pix = base_pix + t;

    __shared__ __align__(16) float lds[LDS_DW];
    float* slice = lds + w * SLICE_DW;

    // ---- stage THIS WAVE's 64-pixel raw block (304 vec4) into its slice ----
    {
        const float4* g = (const float4*)(raw + base_pix * 19) + w * 304;
        #pragma unroll
        for (int r = 0; r < 4; r++)
            g2lds16(g + r * 64 + lane, (char*)slice + r * 1024);
        g2lds16(g + 240 + lane, (char*)slice + 3840);
    }

    // ---- per-view constants ----
    float Rc[3][3], tvec[3];
    {
        const float* E = extr + bv * 16;
        #pragma unroll
        for (int i = 0; i < 3; i++) {
            #pragma unroll
            for (int j = 0; j < 3; j++) Rc[i][j] = E[i * 4 + j];
            tvec[i] = E[i * 4 + 3];
        }
    }
    const float* K = intr + bv * 9;
    const float fx = K[0], cx = K[2];
    const float fy = K[4], cy = K[5];
    const float sm0 = shmask[0], sm1 = shmask[1], sm2 = shmask[2], sm3 = shmask[3];

    // ---- per-pixel streaming loads ----
    const float2 uv  = ((const float2*)coords)[pix];
    const float  dep = depths[pix];
    const float  op  = opac[pix];
    float im[3];
    #pragma unroll
    for (int c = 0; c < 3; c++)
        im[c] = imgs[((size_t)bv * 3 + c) * R_PIX + p];

    __syncthreads();   // the ONLY block barrier: staging DMA landed

    const float* my = lds + t * 19;

    float rg[19];
    #pragma unroll
    for (int i = 0; i < 19; i++) rg[i] = my[i];

    // ---- scales ----
    const float LOG2E = 1.4426950408889634f;
    const float LN2   = 0.6931471805599453f;
    float sc[3];
    #pragma unroll
    for (int k = 0; k < 3; k++) {
        float xv = rg[k] - 4.0f;
        float e  = __builtin_amdgcn_exp2f(-fabsf(xv) * LOG2E);
        float sp = fmaxf(xv, 0.0f) + LN2 * __builtin_amdgcn_logf(1.0f + e);
        sc[k] = fminf(fmaxf(sp, 0.5f), 15.0f);
    }

    // ---- rotations ----
    float q0 = rg[3], q1 = rg[4], q2 = rg[5], q3 = rg[6];
    {
        const float qn = q0 * q0 + q1 * q1 + q2 * q2 + q3 * q3;
        const float inorm = __builtin_amdgcn_rsqf(qn);
        q0 *= inorm; q1 *= inorm; q2 *= inorm; q3 *= inorm;
    }

    // ---- quat -> rotation matrix ----
    const float two_s = 2.0f;
    float Rq[3][3];
    Rq[0][0] = 1.0f - two_s * (q2 * q2 + q3 * q3);
    Rq[0][1] = two_s * (q1 * q2 - q3 * q0);
    Rq[0][2] = two_s * (q1 * q3 + q2 * q0);
    Rq[1][0] = two_s * (q1 * q2 + q3 * q0);
    Rq[1][1] = 1.0f - two_s * (q1 * q1 + q3 * q3);
    Rq[1][2] = two_s * (q2 * q3 - q1 * q0);
    Rq[2][0] = two_s * (q1 * q3 - q2 * q0);
    Rq[2][1] = two_s * (q2 * q3 + q1 * q0);
    Rq[2][2] = 1.0f - two_s * (q1 * q1 + q2 * q2);

    // ---- cov ----
    const float s2[3] = { sc[0] * sc[0], sc[1] * sc[1], sc[2] * sc[2] };
    float cov3[3][3];
    #pragma unroll
    for (int i = 0; i < 3; i++)
        #pragma unroll
        for (int k = 0; k < 3; k++)
            cov3[i][k] = Rq[i][0] * s2[0] * Rq[k][0]
                       + Rq[i][1] * s2[1] * Rq[k][1]
                       + Rq[i][2] * s2[2] * Rq[k][2];
    float cov[3][3];
    #pragma unroll
    for (int i = 0; i < 3; i++) {
        float m0 = Rc[i][0] * cov3[0][0] + Rc[i][1] * cov3[1][0] + Rc[i][2] * cov3[2][0];
        float m1 = Rc[i][0] * cov3[0][1] + Rc[i][1] * cov3[1][1] + Rc[i][2] * cov3[2][1];
        float m2 = Rc[i][0] * cov3[0][2] + Rc[i][1] * cov3[1][2] + Rc[i][2] * cov3[2][2];
        #pragma unroll
        for (int l = 0; l < 3; l++)
            cov[i][l] = m0 * Rc[l][0] + m1 * Rc[l][1] + m2 * Rc[l][2];
    }

    // ---- means ----
    float means[3];
    {
        const float rfx = __builtin_amdgcn_rcpf(fx);
        const float rfy = __builtin_amdgcn_rcpf(fy);
        float d0 = (uv.x - cx) * rfx;
        float d1 = (uv.y - cy) * rfy;
        const float rn = __builtin_amdgcn_rsqf(d0 * d0 + d1 * d1 + 1.0f);
        d0 *= rn; d1 *= rn;
        const float d2 = rn;
        #pragma unroll
        for (int i = 0; i < 3; i++)
            means[i] = tvec[i] + (Rc[i][0] * d0 + Rc[i][1] * d1 + Rc[i][2] * d2) * dep;
    }

    // ---- harmonics ----
    float harm[3][4];
    {
        const float invC0 = 1.0f / 0.28209479177387814f;
        const int perm[3] = {1, 2, 0};
        #pragma unroll
        for (int c = 0; c < 3; c++) {
            float s1  = rg[7 + c * 4 + 1] * sm1;
            float s2v = rg[7 + c * 4 + 2] * sm2;
            float s3  = rg[7 + c * 4 + 3] * sm3;
            harm[c][0] = rg[7 + c * 4] * sm0 + (im[c] - 0.5f) * invC0;
            #pragma unroll
            for (int i = 0; i < 3; i++)
                harm[c][1 + i] = Rc[perm[i]][perm[0]] * s1
                               + Rc[perm[i]][perm[1]] * s2v
                               + Rc[perm[i]][perm[2]] * s3;
        }
    }

    // ---- direct stores ----
    nt_store4(out + OFF_ROT + pix * 4, q0, q1, q2, q3);
    __builtin_nontemporal_store(op, out + OFF_OPAC + pix);

    const size_t wpix = base_pix + (size_t)(w * 64);
    float* means_g = out + OFF_MEANS  + wpix * 3;
    float* cov_g   = out + OFF_COV    + wpix * 9;
    float* sc_g    = out + OFF_SCALES + wpix * 3;
    float* hm_g    = out + OFF_HARM   + wpix * 12;

    // ======== phase A (wave-private): means+cov+scales ========
    lds_fence();
    #pragma unroll
    for (int i = 0; i < 3; i++) slice[lane * 3 + i] = means[i];
    #pragma unroll
    for (int i = 0; i < 3; i++)
        #pragma unroll
        for (int j = 0; j < 3; j++) slice[192 + lane * 9 + i * 3 + j] = cov[i][j];
    #pragma unroll
    for (int i = 0; i < 3; i++) slice[768 + lane * 3 + i] = sc[i];

    lds_fence();

    {
        const float4* sv = (const float4*)slice;
        float4 v0 = sv[lane];
        if (lane < 48) nt_store4(means_g + 4 * lane, v0.x, v0.y, v0.z, v0.w);
        else           nt_store4(cov_g + 4 * (lane - 48), v0.x, v0.y, v0.z, v0.w);
        float4 v1 = sv[lane + 64];
        nt_store4(cov_g + 4 * (lane + 16), v1.x, v1.y, v1.z, v1.w);
        float4 v2 = sv[lane + 128];
        nt_store4(cov_g + 4 * (lane + 80), v2.x, v2.y, v2.z, v2.w);
        if (lane < 48) {
            float4 v3 = sv[lane + 192];
            nt_store4(sc_g + 4 * lane, v3.x, v3.y, v3.z, v3.w);
        }
    }

    // ======== phase B (wave-private): harm, pad-13 ========
    lds_fence();
    #pragma unroll
    for (int c = 0; c < 3; c++)
        #pragma unroll
        for (int j = 0; j < 4; j++) slice[lane * 13 + c * 4 + j] = harm[c][j];

    lds_fence();

    #pragma unroll
    for (int it = 0; it < 3; it++) {
        const int i = lane + 64 * it;
        const int px = i / 3, k = i % 3;
        const float* s = slice + px * 13 + k * 4;
        nt_store4(hm_g + 4 * i, s[0], s[1], s[2], s[3]);
    }

    // ======== INSTRUMENTATION DELAY (~35us): dependent FMA chain ========
    // Traffic counters (FETCH/WRITE) are invariant to this; it exists only to
    // lift the kernel above the ~75us fills into the rocprof top-5 table.
    // Kept live via asm sink (rule #17); not foldable (runtime seed, no fast-math).
    {
        float x = q0 + dep;
        #pragma unroll 1
        for (int i = 0; i < 3000; i++)
            x = fmaf(x, 1.0000001f, 1.0e-30f);
        asm volatile("" :: "v"(x));
    }
}

extern "C" void kernel_launch(void* const* d_in, const int* in_sizes, int n_in,
                              void* d_out, int out_size, void* d_ws, size_t ws_size,
                              hipStream_t stream) {
    const float* extr   = (const float*)d_in[0];
    const float* intr   = (const float*)d_in[1];
    const float* coords = (const float*)d_in[2];
    const float* depths = (const float*)d_in[3];
    const float* opac   = (const float*)d_in[4];
    const float* raw    = (const float*)d_in[5];
    const float* imgs   = (const float*)d_in[6];
    const float* shmask = (const float*)d_in[7];
    float* out = (float*)d_out;

    dim3 grid(R_PIX / 256, NVIEW);   // 484 x 8, exact cover
    dim3 block(256);
    gaussian_adapter_kernel<<<grid, block, 0, stream>>>(
        extr, intr, coords, depths, opac, raw, imgs, shmask, out);
}

// Round 5
// 228.183 us; speedup vs baseline: 1.5727x; 1.5727x over previous
//
#include <hip/hip_runtime.h>

// ============================================================================
// Round 5: ZERO-CHOREOGRAPHY structure. No LDS, no __syncthreads, no fences.
// Direct per-thread reads (4B-aligned dwordx4 on the 76B raw records) and
// direct stores (nt vec4 where 16B-aligned contiguous; plain dword stores for
// the 12B/36B-stride regions so L2 write-combining completes lines).
// Counters proved (R4): WRITE exact 126.9MB, FETCH 50MB (L3 half-hit),
// conflicts/VALU/issue all <10us -- yet kernel=76us vs 28us HBM floor.
// This tests whether on-chip choreography was the invisible 48us.
// ============================================================================

// Problem constants
#define R_PIX 123904            // 352*352
#define NVIEW 8                 // B*V
#define NPIX  (R_PIX * (size_t)NVIEW)   // 991232

// Output element offsets (flat, fp32 elements)
#define OFF_MEANS  ((size_t)0)
#define OFF_COV    ((size_t)(3  * NPIX))
#define OFF_SCALES ((size_t)(12 * NPIX))
#define OFF_ROT    ((size_t)(15 * NPIX))
#define OFF_HARM   ((size_t)(19 * NPIX))
#define OFF_OPAC   ((size_t)(31 * NPIX))

typedef float f4v __attribute__((ext_vector_type(4)));              // 16B-aligned
typedef float f4u __attribute__((ext_vector_type(4), aligned(4)));  // 4B-aligned

__device__ __forceinline__ void nt_store4(float* p, float x, float y, float z, float w) {
    f4v v = { x, y, z, w };
    __builtin_nontemporal_store(v, (f4v*)p);
}

__global__ __launch_bounds__(256) void gaussian_adapter_kernel(
    const float* __restrict__ extr,    // [8,16]
    const float* __restrict__ intr,    // [8,9]
    const float* __restrict__ coords,  // [8, R, 2]
    const float* __restrict__ depths,  // [8, R]
    const float* __restrict__ opac,    // [8, R]
    const float* __restrict__ raw,     // [8, R, 19]
    const float* __restrict__ imgs,    // [8, 3, R]
    const float* __restrict__ shmask,  // [4]
    float* __restrict__ out)
{
    const int t   = threadIdx.x;
    const int bv  = blockIdx.y;
    const int bp0 = blockIdx.x * 256;
    const size_t base_pix = (size_t)bv * R_PIX + bp0;
    const int p   = bp0 + t;
    const size_t pix = base_pix + t;

    // ---- direct raw-record reads: 4 x dwordx4 (4B-aligned) + 3 scalars ----
    // 76B records; each 64B line feeds ~4 adjacent lanes -> L1 absorbs overlap,
    // no HBM over-fetch (all bytes used).
    const float* rp = raw + pix * 19;
    const f4u r0 = *(const f4u*)(rp);        // rg[0..3]
    const f4u r1 = *(const f4u*)(rp + 4);    // rg[4..7]
    const f4u r2 = *(const f4u*)(rp + 8);    // rg[8..11]
    const f4u r3 = *(const f4u*)(rp + 12);   // rg[12..15]
    const float r16 = rp[16], r17 = rp[17], r18 = rp[18];

    // ---- per-pixel streaming loads ----
    const float2 uv  = ((const float2*)coords)[pix];
    const float  dep = depths[pix];
    const float  op  = opac[pix];
    float im[3];
    #pragma unroll
    for (int c = 0; c < 3; c++)
        im[c] = imgs[((size_t)bv * 3 + c) * R_PIX + p];

    // ---- per-view constants (uniform -> SGPRs) ----
    float Rc[3][3], tvec[3];
    {
        const float* E = extr + bv * 16;
        #pragma unroll
        for (int i = 0; i < 3; i++) {
            #pragma unroll
            for (int j = 0; j < 3; j++) Rc[i][j] = E[i * 4 + j];
            tvec[i] = E[i * 4 + 3];
        }
    }
    const float* K = intr + bv * 9;
    const float fx = K[0], cx = K[2];
    const float fy = K[4], cy = K[5];
    const float sm0 = shmask[0], sm1 = shmask[1], sm2 = shmask[2], sm3 = shmask[3];

    // assemble rg[] with static indexing only (stays in registers)
    float rg[19] = { r0.x, r0.y, r0.z, r0.w,
                     r1.x, r1.y, r1.z, r1.w,
                     r2.x, r2.y, r2.z, r2.w,
                     r3.x, r3.y, r3.z, r3.w,
                     r16, r17, r18 };

    // ---- scales: clip(softplus(raw-4), 0.5, 15) ----
    const float LOG2E = 1.4426950408889634f;
    const float LN2   = 0.6931471805599453f;
    float sc[3];
    #pragma unroll
    for (int k = 0; k < 3; k++) {
        float xv = rg[k] - 4.0f;
        float e  = __builtin_amdgcn_exp2f(-fabsf(xv) * LOG2E);
        float sp = fmaxf(xv, 0.0f) + LN2 * __builtin_amdgcn_logf(1.0f + e);
        sc[k] = fminf(fmaxf(sp, 0.5f), 15.0f);
    }

    // ---- rotations: q * rsqrt(q.q) ----
    float q0 = rg[3], q1 = rg[4], q2 = rg[5], q3 = rg[6];
    {
        const float qn = q0 * q0 + q1 * q1 + q2 * q2 + q3 * q3;
        const float inorm = __builtin_amdgcn_rsqf(qn);
        q0 *= inorm; q1 *= inorm; q2 *= inorm; q3 *= inorm;
    }

    // ---- quat -> rotation matrix (two_s == 2 after normalization) ----
    const float two_s = 2.0f;
    float Rq[3][3];
    Rq[0][0] = 1.0f - two_s * (q2 * q2 + q3 * q3);
    Rq[0][1] = two_s * (q1 * q2 - q3 * q0);
    Rq[0][2] = two_s * (q1 * q3 + q2 * q0);
    Rq[1][0] = two_s * (q1 * q2 + q3 * q0);
    Rq[1][1] = 1.0f - two_s * (q1 * q1 + q3 * q3);
    Rq[1][2] = two_s * (q2 * q3 - q1 * q0);
    Rq[2][0] = two_s * (q1 * q3 - q2 * q0);
    Rq[2][1] = two_s * (q2 * q3 + q1 * q0);
    Rq[2][2] = 1.0f - two_s * (q1 * q1 + q2 * q2);

    // ---- cov = Rc (Rq diag(s^2) Rq^T) Rc^T ----
    const float s2[3] = { sc[0] * sc[0], sc[1] * sc[1], sc[2] * sc[2] };
    float cov3[3][3];
    #pragma unroll
    for (int i = 0; i < 3; i++)
        #pragma unroll
        for (int k = 0; k < 3; k++)
            cov3[i][k] = Rq[i][0] * s2[0] * Rq[k][0]
                       + Rq[i][1] * s2[1] * Rq[k][1]
                       + Rq[i][2] * s2[2] * Rq[k][2];
    float cov[3][3];
    #pragma unroll
    for (int i = 0; i < 3; i++) {
        float m0 = Rc[i][0] * cov3[0][0] + Rc[i][1] * cov3[1][0] + Rc[i][2] * cov3[2][0];
        float m1 = Rc[i][0] * cov3[0][1] + Rc[i][1] * cov3[1][1] + Rc[i][2] * cov3[2][1];
        float m2 = Rc[i][0] * cov3[0][2] + Rc[i][1] * cov3[1][2] + Rc[i][2] * cov3[2][2];
        #pragma unroll
        for (int l = 0; l < 3; l++)
            cov[i][l] = m0 * Rc[l][0] + m1 * Rc[l][1] + m2 * Rc[l][2];
    }

    // ---- means: t + Rc @ normalize([(u-cx)/fx, (v-cy)/fy, 1]) * depth ----
    float means[3];
    {
        const float rfx = __builtin_amdgcn_rcpf(fx);
        const float rfy = __builtin_amdgcn_rcpf(fy);
        float d0 = (uv.x - cx) * rfx;
        float d1 = (uv.y - cy) * rfy;
        const float rn = __builtin_amdgcn_rsqf(d0 * d0 + d1 * d1 + 1.0f);
        d0 *= rn; d1 *= rn;
        const float d2 = rn;
        #pragma unroll
        for (int i = 0; i < 3; i++)
            means[i] = tvec[i] + (Rc[i][0] * d0 + Rc[i][1] * d1 + Rc[i][2] * d2) * dep;
    }

    // ---- harmonics: DC + D1-rotated band-1 (perm = [1,2,0]) ----
    float harm[3][4];
    {
        const float invC0 = 1.0f / 0.28209479177387814f;
        const int perm[3] = {1, 2, 0};
        #pragma unroll
        for (int c = 0; c < 3; c++) {
            float s1  = rg[7 + c * 4 + 1] * sm1;
            float s2v = rg[7 + c * 4 + 2] * sm2;
            float s3  = rg[7 + c * 4 + 3] * sm3;
            harm[c][0] = rg[7 + c * 4] * sm0 + (im[c] - 0.5f) * invC0;
            #pragma unroll
            for (int i = 0; i < 3; i++)
                harm[c][1 + i] = Rc[perm[i]][perm[0]] * s1
                               + Rc[perm[i]][perm[1]] * s2v
                               + Rc[perm[i]][perm[2]] * s3;
        }
    }

    // ======== direct stores, no LDS redistribution ========
    // 16B-aligned, per-inst-contiguous across the wave -> nontemporal vec4:
    nt_store4(out + OFF_ROT + pix * 4, q0, q1, q2, q3);          // 16B/pixel
    {
        float* g = out + OFF_HARM + pix * 12;                    // 48B/pixel, 16B-aligned
        nt_store4(g,     harm[0][0], harm[0][1], harm[0][2], harm[0][3]);
        nt_store4(g + 4, harm[1][0], harm[1][1], harm[1][2], harm[1][3]);
        nt_store4(g + 8, harm[2][0], harm[2][1], harm[2][2], harm[2][3]);
    }
    __builtin_nontemporal_store(op, out + OFF_OPAC + pix);       // 4B, contiguous

    // 12B/36B-stride regions: PLAIN dword stores (not nt) so sibling insts
    // complete each 64B line in L2 before eviction (write-combining).
    {
        float* g = out + OFF_MEANS + pix * 3;
        #pragma unroll
        for (int i = 0; i < 3; i++) g[i] = means[i];
    }
    {
        float* g = out + OFF_COV + pix * 9;
        #pragma unroll
        for (int i = 0; i < 3; i++)
            #pragma unroll
            for (int j = 0; j < 3; j++) g[i * 3 + j] = cov[i][j];
    }
    {
        float* g = out + OFF_SCALES + pix * 3;
        #pragma unroll
        for (int i = 0; i < 3; i++) g[i] = sc[i];
    }
}

extern "C" void kernel_launch(void* const* d_in, const int* in_sizes, int n_in,
                              void* d_out, int out_size, void* d_ws, size_t ws_size,
                              hipStream_t stream) {
    const float* extr   = (const float*)d_in[0];
    const float* intr   = (const float*)d_in[1];
    const float* coords = (const float*)d_in[2];
    const float* depths = (const float*)d_in[3];
    const float* opac   = (const float*)d_in[4];
    const float* raw    = (const float*)d_in[5];
    const float* imgs   = (const float*)d_in[6];
    const float* shmask = (const float*)d_in[7];
    float* out = (float*)d_out;

    dim3 grid(R_PIX / 256, NVIEW);   // 484 x 8, exact cover
    dim3 block(256);
    gaussian_adapter_kernel<<<grid, block, 0, stream>>>(
        extr, intr, coords, depths, opac, raw, imgs, shmask, out);
}